// Round 4
// baseline (142928.760 us; speedup 1.0000x reference)
//
#include <hip/hip_runtime.h>
#include <math.h>

// Problem constants
#define Bsz   256
#define Hd    512
#define Din   512
#define Lenc  48
#define Look  10
#define G4    2048     // 4*H
#define LabStride 58   // LENC + LDEC
#define StartIdx  48   // LDEC + LENC - LOOK

typedef unsigned short u16;
using bfrag = __attribute__((ext_vector_type(8))) short;   // 8 bf16 (4 VGPRs)
using f32x4 = __attribute__((ext_vector_type(4))) float;   // 4 fp32 acc

#define MFMA16(a,b,c) __builtin_amdgcn_mfma_f32_16x16x32_bf16((a),(b),(c),0,0,0)

__device__ __forceinline__ u16 f2bf(float f){
  unsigned u = __float_as_uint(f);
  u += 0x7FFFu + ((u>>16)&1u);               // RNE
  return (u16)(u>>16);
}
__device__ __forceinline__ float bf2f(u16 h){ return __uint_as_float(((unsigned)h)<<16); }
__device__ __forceinline__ float sigm(float x){ return 1.f/(1.f+__expf(-x)); }

// ---- 32x32 output tile per wave (M=32), K-loop of 16x16x32 MFMAs ----
// A: activations [m][k] row-major (lda), W: weights [n][k] row-major (ldw) == B^T.
// Frag layout (m89/m91): A row = lane&15, k = 8*(lane>>4)+j ; same for W (row->n).
// acc[4] = [mi*2+ni], D: col(n)=lane&15, row(m)=4*(lane>>4)+reg.
template<int K>
__device__ __forceinline__ void mm32(const u16* __restrict__ A, int lda,
                                     const u16* __restrict__ W, int ldw,
                                     f32x4* acc, int lane){
  const int rr = lane & 15, ko = (lane>>4)<<3;
  const u16* a0 = A + (size_t)rr*lda + ko;
  const u16* a1 = a0 + 16*(size_t)lda;
  const u16* w0 = W + (size_t)rr*ldw + ko;
  const u16* w1 = w0 + 16*(size_t)ldw;
#pragma unroll
  for(int k=0;k<K;k+=32){
    bfrag av0 = *(const bfrag*)(a0+k);
    bfrag av1 = *(const bfrag*)(a1+k);
    bfrag wv0 = *(const bfrag*)(w0+k);
    bfrag wv1 = *(const bfrag*)(w1+k);
    acc[0] = MFMA16(av0,wv0,acc[0]);
    acc[1] = MFMA16(av0,wv1,acc[1]);
    acc[2] = MFMA16(av1,wv0,acc[2]);
    acc[3] = MFMA16(av1,wv1,acc[3]);
  }
}

// ---- 16x32 tile per wave (M=16): acc[2] = [ni]; D row=4*(lane>>4)+j, col=ni*16+(lane&15)
template<int K>
__device__ __forceinline__ void mm16(const u16* __restrict__ A, int lda,
                                     const u16* __restrict__ W, int ldw,
                                     f32x4* acc, int lane){
  const int rr = lane & 15, ko = (lane>>4)<<3;
  const u16* a0 = A + (size_t)rr*lda + ko;
  const u16* w0 = W + (size_t)rr*ldw + ko;
  const u16* w1 = w0 + 16*(size_t)ldw;
#pragma unroll
  for(int k=0;k<K;k+=32){
    bfrag av  = *(const bfrag*)(a0+k);
    bfrag wv0 = *(const bfrag*)(w0+k);
    bfrag wv1 = *(const bfrag*)(w1+k);
    acc[0] = MFMA16(av,wv0,acc[0]);
    acc[1] = MFMA16(av,wv1,acc[1]);
  }
}

// ---------------- setup kernels ----------------
__global__ void k_cvt(const float* __restrict__ s, u16* __restrict__ d, int n){
  for(int i=blockIdx.x*blockDim.x+threadIdx.x; i<n; i+=gridDim.x*blockDim.x) d[i]=f2bf(s[i]);
}

// Wih_tg is (2048 x 513): col0 -> c0 (fp32), cols 1..512 -> packed bf16
__global__ void k_cvt_tg(const float* __restrict__ s, u16* __restrict__ d, float* __restrict__ c0){
  int stride=gridDim.x*blockDim.x;
  for(int i=blockIdx.x*blockDim.x+threadIdx.x; i<G4*Hd; i+=stride){
    int n=i>>9, k=i&511;
    d[i]=f2bf(s[n*513+1+k]);
  }
  for(int n=blockIdx.x*blockDim.x+threadIdx.x; n<G4; n+=stride) c0[n]=s[n*513];
}

__global__ void k_init(const float* __restrict__ label, float* __restrict__ lab){
  int b=threadIdx.x;
  if(b<Bsz) lab[b]=label[b*LabStride+StartIdx];
}

// wi_seq[l][b][h] = input[b][l][:] . Wi_w[h][:] + Wi_b[h]   (M=B*Lenc rows (b,l))
__global__ __launch_bounds__(64) void k_wi(const u16* __restrict__ inpb, const u16* __restrict__ Wi,
                     const float* __restrict__ Wib, float* __restrict__ wi_seq){
  int lane=threadIdx.x;
  int r0=blockIdx.x*32, h0=blockIdx.y*32;
  f32x4 acc[4]={};
  mm32<Din>(inpb+(size_t)r0*Din, Din, Wi+(size_t)h0*Din, Din, acc, lane);
  int cr=(lane>>4)*4, cc=lane&15;
  for(int mi=0;mi<2;mi++)for(int ni=0;ni<2;ni++){
    int h=h0+ni*16+cc; float bias=Wib[h];
    f32x4 a=acc[mi*2+ni];
    for(int j=0;j<4;j++){
      int g=r0+mi*16+cr+j;
      int b=g/Lenc, l=g-b*Lenc;
      wi_seq[((size_t)l*Bsz+b)*Hd + h] = a[j]+bias;
    }
  }
}

// C = A1 @ W[:, :512]^T + A2 @ W[:, 512:]^T   (fp32 out; used for wt and wh)
__global__ __launch_bounds__(128) void k_dual(const u16* __restrict__ A1, const u16* __restrict__ A2,
      const u16* __restrict__ W, float* __restrict__ C){
  int lane=threadIdx.x&63, wid=threadIdx.x>>6;
  int b0=blockIdx.x*32, h0=blockIdx.y*32;
  f32x4 acc[4]={};
  if(wid==0) mm32<Hd>(A1+(size_t)b0*Hd, Hd, W+(size_t)h0*1024,     1024, acc, lane);
  else       mm32<Hd>(A2+(size_t)b0*Hd, Hd, W+(size_t)h0*1024+512, 1024, acc, lane);
  __shared__ f32x4 red[4*64];
  if(wid==1){ for(int i=0;i<4;i++) red[i*64+lane]=acc[i]; }
  __syncthreads();
  if(wid!=0) return;
  for(int i=0;i<4;i++) acc[i]+=red[i*64+lane];
  int cr=(lane>>4)*4, cc=lane&15;
  for(int mi=0;mi<2;mi++)for(int ni=0;ni<2;ni++){
    int h=h0+ni*16+cc;
    f32x4 a=acc[mi*2+ni];
    for(int j=0;j<4;j++){
      int b=b0+mi*16+cr+j;
      C[(size_t)b*Hd+h]=a[j];
    }
  }
}

// ============ fused sp-scan + mid-scan (row-local over batch) ============
// 16 blocks x 1024 threads. Block owns 16 batch rows; wave w owns h/d cols [32w,32w+32).
// State: he/ce/hm (bf16) in LDS, cell c's in registers. 48 steps, no grid sync.
#define RB 16
#define LDP 520   // LDS row pitch (u16): 520*2=1040B -> stride%128B!=0, 2-way bank alias only

__global__ __launch_bounds__(1024) void k_scan(
    const float* __restrict__ finp,      // [B][48][512] f32 (x_i for xmod)
    const float* __restrict__ wiseq,     // [l][b][h] f32
    const float* __restrict__ wtf,       // [b][h] f32
    const u16*  __restrict__ web,        // We  [512][1024] bf16
    const u16*  __restrict__ vdb,        // Vd  [512][512]  bf16
    const float* __restrict__ vd_b,      // [512]
    const u16*  __restrict__ wspih, const u16* __restrict__ wsphh,
    const float* __restrict__ bih_sp, const float* __restrict__ bhh_sp,
    const u16*  __restrict__ wmidih, const u16* __restrict__ wmidhh,
    const float* __restrict__ bih_mid, const float* __restrict__ bhh_mid,
    u16* __restrict__ mid2b)             // out: [l][b][h] bf16
{
  __shared__ __align__(16) u16 heL[RB*LDP];
  __shared__ __align__(16) u16 ceL[RB*LDP];
  __shared__ __align__(16) u16 sxL[RB*LDP];  // spre, then xmod
  __shared__ __align__(16) u16 hmL[RB*LDP];
  __shared__ float pm[16*RB];
  __shared__ float ps[16*RB];

  const int lane = threadIdx.x & 63, w = threadIdx.x >> 6;
  const int brow = blockIdx.x * RB;
  const int h0 = w * 32;
  const int g = lane >> 4, c = lane & 15;

  for(int i=threadIdx.x; i<RB*LDP; i+=1024){ heL[i]=0; ceL[i]=0; hmL[i]=0; }

  // per-wave constants (biases for this wave's 32-col patch, wt patch)
  float bsp0[2],bsp1[2],bsp2[2],bsp3[2], bm0[2],bm1[2],bm2[2],bm3[2], vbias[2];
  f32x4 wt_r[2];
#pragma unroll
  for(int ni=0;ni<2;ni++){
    int col = h0 + ni*16 + c;
    vbias[ni] = vd_b[col];
    bsp0[ni]=bih_sp[0*Hd+col]+bhh_sp[0*Hd+col];
    bsp1[ni]=bih_sp[1*Hd+col]+bhh_sp[1*Hd+col];
    bsp2[ni]=bih_sp[2*Hd+col]+bhh_sp[2*Hd+col];
    bsp3[ni]=bih_sp[3*Hd+col]+bhh_sp[3*Hd+col];
    bm0[ni]=bih_mid[0*Hd+col]+bhh_mid[0*Hd+col];
    bm1[ni]=bih_mid[1*Hd+col]+bhh_mid[1*Hd+col];
    bm2[ni]=bih_mid[2*Hd+col]+bhh_mid[2*Hd+col];
    bm3[ni]=bih_mid[3*Hd+col]+bhh_mid[3*Hd+col];
#pragma unroll
    for(int j=0;j<4;j++) wt_r[ni][j] = wtf[(size_t)(brow+4*g+j)*Hd + col];
  }
  __syncthreads();

  f32x4 c_sp[2]={}; f32x4 c_mid[2]={};

  for(int l=0;l<Lenc;l++){
    // ---- P1: spre = tanh([he,ce]@We^T + wi + wt), write bf16 to sxL ----
    f32x4 pacc[2]={};
    mm16<Hd>(heL, LDP, web + (size_t)h0*1024,       1024, pacc, lane);
    mm16<Hd>(ceL, LDP, web + (size_t)h0*1024 + 512, 1024, pacc, lane);
#pragma unroll
    for(int ni=0;ni<2;ni++){
      int col=h0+ni*16+c;
#pragma unroll
      for(int j=0;j<4;j++){
        int row=4*g+j;
        float v = pacc[ni][j] + wiseq[((size_t)l*Bsz + brow+row)*Hd + col] + wt_r[ni][j];
        sxL[row*LDP + col] = f2bf(tanhf(v));
      }
    }
    __syncthreads();

    // ---- P2: score tile = spre @ Vd^T (d-patch = this wave's 32 cols) ----
    f32x4 sacc[2]={};
    mm16<Hd>(sxL, LDP, vdb + (size_t)h0*Hd, Hd, sacc, lane);

    // ---- P3: softmax over d=512 (in-reg + 2-stage LDS reduce), xmod -> sxL ----
    float sc0[4], sc1[4], xv0[4], xv1[4];
#pragma unroll
    for(int j=0;j<4;j++){
      int b = brow + 4*g + j;
      xv0[j] = finp[((size_t)b*Lenc + l)*Din + h0 + c];
      xv1[j] = finp[((size_t)b*Lenc + l)*Din + h0 + 16 + c];
      sc0[j] = sacc[0][j] + vbias[0];
      sc1[j] = sacc[1][j] + vbias[1];
    }
    float pmax[4];
#pragma unroll
    for(int j=0;j<4;j++){
      float m = fmaxf(sc0[j], sc1[j]);
      m = fmaxf(m, __shfl_xor(m,1));
      m = fmaxf(m, __shfl_xor(m,2));
      m = fmaxf(m, __shfl_xor(m,4));
      m = fmaxf(m, __shfl_xor(m,8));
      pmax[j]=m;
    }
    if(c==0){
#pragma unroll
      for(int j=0;j<4;j++) pm[w*RB + 4*g + j] = pmax[j];
    }
    __syncthreads();
    float ev0[4], ev1[4], psum[4];
#pragma unroll
    for(int j=0;j<4;j++){
      float m=-1e30f;
      for(int ww=0;ww<16;ww++) m = fmaxf(m, pm[ww*RB + 4*g + j]);
      ev0[j]=__expf(sc0[j]-m);
      ev1[j]=__expf(sc1[j]-m);
      float s=ev0[j]+ev1[j];
      s += __shfl_xor(s,1);
      s += __shfl_xor(s,2);
      s += __shfl_xor(s,4);
      s += __shfl_xor(s,8);
      psum[j]=s;
    }
    if(c==0){
#pragma unroll
      for(int j=0;j<4;j++) ps[w*RB + 4*g + j] = psum[j];
    }
    __syncthreads();
#pragma unroll
    for(int j=0;j<4;j++){
      float s=0.f;
      for(int ww=0;ww<16;ww++) s += ps[ww*RB + 4*g + j];
      float inv = 1.f/s;
      int row=4*g+j;
      sxL[row*LDP + h0 + c]      = f2bf(xv0[j]*ev0[j]*inv);
      sxL[row*LDP + h0 + 16 + c] = f2bf(xv1[j]*ev1[j]*inv);
    }
    __syncthreads();

    // ---- P4: sp gates = xmod@Wih^T + he_prev@Whh^T ----
    f32x4 gq0[2]={},gq1[2]={},gq2[2]={},gq3[2]={};
    mm16<Hd>(sxL, LDP, wspih + ((size_t)(0*Hd)+h0)*Hd, Hd, gq0, lane);
    mm16<Hd>(heL, LDP, wsphh + ((size_t)(0*Hd)+h0)*Hd, Hd, gq0, lane);
    mm16<Hd>(sxL, LDP, wspih + ((size_t)(1*Hd)+h0)*Hd, Hd, gq1, lane);
    mm16<Hd>(heL, LDP, wsphh + ((size_t)(1*Hd)+h0)*Hd, Hd, gq1, lane);
    mm16<Hd>(sxL, LDP, wspih + ((size_t)(2*Hd)+h0)*Hd, Hd, gq2, lane);
    mm16<Hd>(heL, LDP, wsphh + ((size_t)(2*Hd)+h0)*Hd, Hd, gq2, lane);
    mm16<Hd>(sxL, LDP, wspih + ((size_t)(3*Hd)+h0)*Hd, Hd, gq3, lane);
    mm16<Hd>(heL, LDP, wsphh + ((size_t)(3*Hd)+h0)*Hd, Hd, gq3, lane);
    __syncthreads();   // all waves done reading heL/sxL before overwrite

    // ---- P5: sp cell update; write he/ce to LDS ----
#pragma unroll
    for(int ni=0;ni<2;ni++){
      int col=h0+ni*16+c;
#pragma unroll
      for(int j=0;j<4;j++){
        int row=4*g+j;
        float ii=sigm (gq0[ni][j]+bsp0[ni]);
        float ff=sigm (gq1[ni][j]+bsp1[ni]);
        float g2=tanhf(gq2[ni][j]+bsp2[ni]);
        float oo=sigm (gq3[ni][j]+bsp3[ni]);
        float c2=ff*c_sp[ni][j] + ii*g2;
        float hv=oo*tanhf(c2);
        c_sp[ni][j]=c2;
        heL[row*LDP+col]=f2bf(hv);
        ceL[row*LDP+col]=f2bf(c2);
      }
    }
    __syncthreads();   // he_l complete (x-input of mid step l)

    // ---- P6: mid gates = he_l@Wih_mid^T + hm_prev@Whh_mid^T ----
    f32x4 mq0[2]={},mq1[2]={},mq2[2]={},mq3[2]={};
    mm16<Hd>(heL, LDP, wmidih + ((size_t)(0*Hd)+h0)*Hd, Hd, mq0, lane);
    mm16<Hd>(hmL, LDP, wmidhh + ((size_t)(0*Hd)+h0)*Hd, Hd, mq0, lane);
    mm16<Hd>(heL, LDP, wmidih + ((size_t)(1*Hd)+h0)*Hd, Hd, mq1, lane);
    mm16<Hd>(hmL, LDP, wmidhh + ((size_t)(1*Hd)+h0)*Hd, Hd, mq1, lane);
    mm16<Hd>(heL, LDP, wmidih + ((size_t)(2*Hd)+h0)*Hd, Hd, mq2, lane);
    mm16<Hd>(hmL, LDP, wmidhh + ((size_t)(2*Hd)+h0)*Hd, Hd, mq2, lane);
    mm16<Hd>(heL, LDP, wmidih + ((size_t)(3*Hd)+h0)*Hd, Hd, mq3, lane);
    mm16<Hd>(hmL, LDP, wmidhh + ((size_t)(3*Hd)+h0)*Hd, Hd, mq3, lane);
    __syncthreads();   // hmL reads done before overwrite

    // ---- P7: mid cell; write hm to LDS + mid2 to global ----
#pragma unroll
    for(int ni=0;ni<2;ni++){
      int col=h0+ni*16+c;
#pragma unroll
      for(int j=0;j<4;j++){
        int row=4*g+j;
        float ii=sigm (mq0[ni][j]+bm0[ni]);
        float ff=sigm (mq1[ni][j]+bm1[ni]);
        float g2=tanhf(mq2[ni][j]+bm2[ni]);
        float oo=sigm (mq3[ni][j]+bm3[ni]);
        float c2=ff*c_mid[ni][j] + ii*g2;
        float hv=oo*tanhf(c2);
        c_mid[ni][j]=c2;
        u16 hb=f2bf(hv);
        hmL[row*LDP+col]=hb;
        mid2b[((size_t)l*Bsz + brow+row)*Hd + col] = hb;
      }
    }
    __syncthreads();   // hm ready for next step
  }
}

// tg cell: x = [lab, dec_in] (col0 handled via c0 in epilogue)
__global__ __launch_bounds__(128) void k_tg(const u16* __restrict__ dec, const u16* __restrict__ ht,
    const u16* __restrict__ Wih, const u16* __restrict__ Whh,
    const float* __restrict__ c0, const float* __restrict__ bih, const float* __restrict__ bhh,
    const float* __restrict__ lab, float* __restrict__ cst, u16* __restrict__ cbf,
    u16* __restrict__ hout, int t0){
  int lane=threadIdx.x&63, wid=threadIdx.x>>6;
  int b0=blockIdx.x*32, h0=blockIdx.y*32;
  f32x4 acc[4][4]={};
  if(!t0){
    if(wid==0){ for(int g=0;g<4;g++) mm32<Hd>(dec+(size_t)b0*Hd, Hd, Wih+((size_t)g*Hd+h0)*Hd, Hd, acc[g], lane); }
    else      { for(int g=0;g<4;g++) mm32<Hd>(ht +(size_t)b0*Hd, Hd, Whh+((size_t)g*Hd+h0)*Hd, Hd, acc[g], lane); }
  }
  __shared__ f32x4 red[16*64];
  if(wid==1){ for(int i=0;i<16;i++) red[i*64+lane]=acc[i>>2][i&3]; }
  __syncthreads();
  if(wid!=0) return;
  for(int i=0;i<16;i++) acc[i>>2][i&3]+=red[i*64+lane];
  int cr=(lane>>4)*4, cc=lane&15;
  for(int mi=0;mi<2;mi++)for(int ni=0;ni<2;ni++){
    int h=h0+ni*16+cc; int tq=mi*2+ni;
    float bi =bih[h]+bhh[h];
    float bff=bih[Hd+h]+bhh[Hd+h];
    float bg =bih[2*Hd+h]+bhh[2*Hd+h];
    float bo =bih[3*Hd+h]+bhh[3*Hd+h];
    float ci=c0[h], cf=c0[Hd+h], cg=c0[2*Hd+h], co=c0[3*Hd+h];
    for(int j=0;j<4;j++){
      int b=b0+mi*16+cr+j;
      size_t ix=(size_t)b*Hd+h;
      float lb=lab[b];
      float ii=sigm(acc[0][tq][j]+bi +lb*ci);
      float ff=sigm(acc[1][tq][j]+bff+lb*cf);
      float gg=tanhf(acc[2][tq][j]+bg +lb*cg);
      float oo=sigm(acc[3][tq][j]+bo +lb*co);
      float cold=t0?0.f:cst[ix];
      float c2=ff*cold+ii*gg;
      float hv=oo*tanhf(c2);
      cst[ix]=c2; cbf[ix]=f2bf(c2); hout[ix]=f2bf(hv);
    }
  }
}

// target = ht @ reg_w^T + reg_b ; out[b*Look+t] and lab update
__global__ __launch_bounds__(64) void k_target(const u16* __restrict__ ht, const float* __restrict__ regw,
     const float* __restrict__ regb, float* __restrict__ outp, float* __restrict__ lab, int t){
  int b=blockIdx.x, lane=threadIdx.x;
  bfrag v=*(const bfrag*)(ht+(size_t)b*Hd+lane*8);
  const float* w=regw+lane*8;
  float a=0;
  for(int j=0;j<8;j++) a+=bf2f((u16)v[j])*w[j];
  for(int o=1;o<64;o<<=1) a+=__shfl_xor(a,o);
  if(lane==0){ float val=a+regb[0]; outp[b*Look+t]=val; lab[b]=val; }
}

// TT = tanh(mid2 @ Wx^T + wh[b] + Wx_b)  (M = Lenc*B rows)
__global__ __launch_bounds__(128) void k_scgemm(const u16* __restrict__ mid2, const u16* __restrict__ Wx,
      const float* __restrict__ Wxb, const float* __restrict__ wh, u16* __restrict__ TT){
  int lane=threadIdx.x&63, wid=threadIdx.x>>6;
  int r0=blockIdx.x*32, h0=blockIdx.y*32;
  f32x4 acc[4]={};
  mm32<256>(mid2+(size_t)r0*Hd + wid*256, Hd, Wx+(size_t)h0*Hd + wid*256, Hd, acc, lane);
  __shared__ f32x4 red[4*64];
  if(wid==1){ for(int i=0;i<4;i++) red[i*64+lane]=acc[i]; }
  __syncthreads();
  if(wid!=0) return;
  for(int i=0;i<4;i++) acc[i]+=red[i*64+lane];
  int cr=(lane>>4)*4, cc=lane&15;
  for(int mi=0;mi<2;mi++)for(int ni=0;ni<2;ni++){
    int h=h0+ni*16+cc; float wb=Wxb[h];
    f32x4 a=acc[mi*2+ni];
    for(int j=0;j<4;j++){
      int row=r0+mi*16+cr+j;
      int b=row&255;
      TT[(size_t)row*Hd+h]=f2bf(tanhf(a[j]+wh[(size_t)b*Hd+h]+wb));
    }
  }
}

// sc[b][l] = TT[row] . V_w + V_b   (row = l*B + b)
__global__ __launch_bounds__(64) void k_scred(const u16* __restrict__ TT, const float* __restrict__ Vw,
      const float* __restrict__ Vb, float* __restrict__ sc){
  int row=blockIdx.x, lane=threadIdx.x;
  bfrag v=*(const bfrag*)(TT+(size_t)row*Hd+lane*8);
  const float* w=Vw+lane*8;
  float a=0;
  for(int j=0;j<8;j++) a+=bf2f((u16)v[j])*w[j];
  for(int o=1;o<64;o<<=1) a+=__shfl_xor(a,o);
  if(lane==0){ int l=row>>8, b=row&255; sc[b*Lenc+l]=a+Vb[0]; }
}

// dec_in[b][h] = sum_l sc[b][l] * mid2[l][b][h]
__global__ __launch_bounds__(256) void k_dec(const float* __restrict__ sc, const u16* __restrict__ mid2,
      u16* __restrict__ dec){
  __shared__ float s[Lenc];
  int b=blockIdx.x, tid=threadIdx.x;
  if(tid<Lenc) s[tid]=sc[b*Lenc+tid];
  __syncthreads();
  for(int h=tid; h<Hd; h+=256){
    float a=0;
    for(int l=0;l<Lenc;l++) a+=s[l]*bf2f(mid2[((size_t)l*Bsz+b)*Hd+h]);
    dec[(size_t)b*Hd+h]=f2bf(a);
  }
}

// ---------------- host ----------------
extern "C" void kernel_launch(void* const* d_in, const int* in_sizes, int n_in,
                              void* d_out, int out_size, void* d_ws, size_t ws_size,
                              hipStream_t stream){
  const float* f_inp    =(const float*)d_in[0];
  const float* f_label  =(const float*)d_in[1];
  const float* f_Wih_sp =(const float*)d_in[2];
  const float* f_Whh_sp =(const float*)d_in[3];
  const float* f_bih_sp =(const float*)d_in[4];
  const float* f_bhh_sp =(const float*)d_in[5];
  const float* f_Wih_tg =(const float*)d_in[6];
  const float* f_Whh_tg =(const float*)d_in[7];
  const float* f_bih_tg =(const float*)d_in[8];
  const float* f_bhh_tg =(const float*)d_in[9];
  const float* f_Wih_mid=(const float*)d_in[10];
  const float* f_Whh_mid=(const float*)d_in[11];
  const float* f_bih_mid=(const float*)d_in[12];
  const float* f_bhh_mid=(const float*)d_in[13];
  const float* f_Wi_w   =(const float*)d_in[14];
  const float* f_Wi_b   =(const float*)d_in[15];
  const float* f_We_w   =(const float*)d_in[16];
  const float* f_Wt_w   =(const float*)d_in[17];
  const float* f_Vd_w   =(const float*)d_in[18];
  const float* f_Vd_b   =(const float*)d_in[19];
  const float* f_Wx_w   =(const float*)d_in[20];
  const float* f_Wx_b   =(const float*)d_in[21];
  const float* f_Wh_w   =(const float*)d_in[22];
  const float* f_V_w    =(const float*)d_in[23];
  const float* f_V_b    =(const float*)d_in[24];
  const float* f_reg_w  =(const float*)d_in[25];
  const float* f_reg_b  =(const float*)d_in[26];
  float* outp=(float*)d_out;

  char* basep=(char*)d_ws; size_t off=0;
  auto alloc=[&](size_t bytes)->void*{ void* r=basep+off; off+=(bytes+255)&~((size_t)255); return r; };

  const size_t BH=(size_t)Bsz*Hd;
  u16*  wspih =(u16*)alloc((size_t)G4*Hd*2);
  u16*  wsphh =(u16*)alloc((size_t)G4*Hd*2);
  u16*  wtgih =(u16*)alloc((size_t)G4*Hd*2);
  u16*  wtghh =(u16*)alloc((size_t)G4*Hd*2);
  u16*  wmidih=(u16*)alloc((size_t)G4*Hd*2);
  u16*  wmidhh=(u16*)alloc((size_t)G4*Hd*2);
  u16*  web   =(u16*)alloc((size_t)Hd*1024*2);
  u16*  wtb   =(u16*)alloc((size_t)Hd*1024*2);
  u16*  whb   =(u16*)alloc((size_t)Hd*1024*2);
  u16*  vdb   =(u16*)alloc((size_t)Hd*Hd*2);
  u16*  wxb   =(u16*)alloc((size_t)Hd*Hd*2);
  u16*  wib   =(u16*)alloc((size_t)Hd*Hd*2);
  u16*  inpb  =(u16*)alloc((size_t)Bsz*Lenc*Din*2);
  float* c0f  =(float*)alloc((size_t)G4*4);
  float* wiseq=(float*)alloc((size_t)Lenc*BH*4);
  u16*  mid2b =(u16*)alloc((size_t)Lenc*BH*2);
  u16*  ttb   =(u16*)alloc((size_t)Lenc*BH*2);
  float* ctf  =(float*)alloc(BH*4);
  u16*  ctb   =(u16*)alloc(BH*2);
  u16*  ht0   =(u16*)alloc(BH*2);
  u16*  ht1   =(u16*)alloc(BH*2);
  u16*  decb  =(u16*)alloc(BH*2);
  float* wtf  =(float*)alloc(BH*4);
  float* whf  =(float*)alloc(BH*4);
  float* labf =(float*)alloc((size_t)Bsz*4);
  float* scf  =(float*)alloc((size_t)Bsz*Lenc*4);

  dim3 cvtg(512), cvtb(256);
  k_cvt<<<cvtg,cvtb,0,stream>>>(f_Wih_sp ,wspih ,G4*Hd);
  k_cvt<<<cvtg,cvtb,0,stream>>>(f_Whh_sp ,wsphh ,G4*Hd);
  k_cvt<<<cvtg,cvtb,0,stream>>>(f_Whh_tg ,wtghh ,G4*Hd);
  k_cvt<<<cvtg,cvtb,0,stream>>>(f_Wih_mid,wmidih,G4*Hd);
  k_cvt<<<cvtg,cvtb,0,stream>>>(f_Whh_mid,wmidhh,G4*Hd);
  k_cvt<<<cvtg,cvtb,0,stream>>>(f_We_w   ,web   ,Hd*1024);
  k_cvt<<<cvtg,cvtb,0,stream>>>(f_Wt_w   ,wtb   ,Hd*1024);
  k_cvt<<<cvtg,cvtb,0,stream>>>(f_Wh_w   ,whb   ,Hd*1024);
  k_cvt<<<cvtg,cvtb,0,stream>>>(f_Vd_w   ,vdb   ,Hd*Hd);
  k_cvt<<<cvtg,cvtb,0,stream>>>(f_Wx_w   ,wxb   ,Hd*Hd);
  k_cvt<<<cvtg,cvtb,0,stream>>>(f_Wi_w   ,wib   ,Hd*Hd);
  k_cvt<<<dim3(1024),cvtb,0,stream>>>(f_inp, inpb, Bsz*Lenc*Din);
  k_cvt_tg<<<cvtg,cvtb,0,stream>>>(f_Wih_tg, wtgih, c0f);
  k_init<<<dim3(1),dim3(256),0,stream>>>(f_label, labf);
  k_wi<<<dim3(384,16),dim3(64),0,stream>>>(inpb, wib, f_Wi_b, wiseq);

  dim3 g816(8,16), b128(128);
  u16 *htR=ht0, *htW=ht1;
  for(int t=0;t<Look;t++){
    int t0 = (t==0)?1:0;
    k_tg<<<g816,b128,0,stream>>>(decb, htR, wtgih, wtghh, c0f, f_bih_tg, f_bhh_tg,
                                 labf, ctf, ctb, htW, t0);
    k_target<<<dim3(Bsz),dim3(64),0,stream>>>(htW, f_reg_w, f_reg_b, outp, labf, t);
    k_dual<<<g816,b128,0,stream>>>(htW, ctb, wtb, wtf);
    k_dual<<<g816,b128,0,stream>>>(htW, ctb, whb, whf);

    k_scan<<<dim3(Bsz/RB),dim3(1024),0,stream>>>(
        f_inp, wiseq, wtf, web, vdb, f_Vd_b,
        wspih, wsphh, f_bih_sp, f_bhh_sp,
        wmidih, wmidhh, f_bih_mid, f_bhh_mid, mid2b);

    k_scgemm<<<dim3(384,16),b128,0,stream>>>(mid2b, wxb, f_Wx_b, whf, ttb);
    k_scred<<<dim3(Lenc*Bsz),dim3(64),0,stream>>>(ttb, f_V_w, f_V_b, scf);
    k_dec<<<dim3(Bsz),dim3(256),0,stream>>>(scf, mid2b, decb);

    u16* tmp=htR; htR=htW; htW=tmp;
  }
}